// Round 3
// baseline (337.655 us; speedup 1.0000x reference)
//
#include <hip/hip_runtime.h>

// MultiHeadAttention (cross-head variant): out = softmax((XWq)(XWk)^T/32 per-token over heads) (XWv) Wo + bo
// Pipeline: merged cast/transpose -> fused QKV bf16 GEMM -> barrier-free per-token wave attention
//           -> out GEMM + bias.
// R8 change: 2-phase slip-pipelined GEMM. R7's 4-phase lockstep paid per phase:
//   barrier + full-wave lgkmcnt(0) drain + MFMA + barrier (LDS pipe and MFMA pipe strictly
//   serialized; 8 barriers/tile) ~= 5350 cyc/tile vs 2484 MFMA content. New structure:
//   2 phases/tile, ONE barrier per phase, no mid-phase barrier, no explicit lgkmcnt(0)
//   (compiler emits counted waits). Waves slip within a phase so one wave's MFMA burst
//   overlaps another's ds_read drain; setprio(1) arbitrates for the MFMA wave (T5).
//   Hazards: same-phase STG vs reads touch disjoint LDS regions (ph1 reads A0,B0,B1 +
//   stages A1(t+1); ph2 reads A1 + stages A0,B0,B1(t+2)); end-of-phase barrier separates
//   cross-phase overwrites; vmcnt(6) at ph2 keeps exactly the newest 6 ops = {A0,B0,B1}(t+2).
//   C stores nontemporal (keep L2 for the staging reuse window).

typedef unsigned short u16;
typedef unsigned int u32;

typedef __bf16 bf16x8 __attribute__((ext_vector_type(8)));
typedef float f32x4 __attribute__((ext_vector_type(4)));

__device__ __forceinline__ u16 f2bf(float f) {
  u32 u = __float_as_uint(f);
  u += 0x7fffu + ((u >> 16) & 1u);   // round-to-nearest-even
  return (u16)(u >> 16);
}
__device__ __forceinline__ float bflo(u32 u) { return __uint_as_float(u << 16); }
__device__ __forceinline__ float bfhi(u32 u) { return __uint_as_float(u & 0xffff0000u); }

// async global->LDS, 16B per lane. LDS dest must be wave-uniform base + lane*16.
__device__ __forceinline__ void load_lds16(const u16* g, u16* l) {
  __builtin_amdgcn_global_load_lds(
      (const __attribute__((address_space(1))) u32*)g,
      (__attribute__((address_space(3))) u32*)l, 16, 0, 0);
}

// ---------------------------------------------------------------- prep (merged)
// blocks [0, 8192): cast x fp32 -> bf16, 8 elems/thread.
// blocks [8192, 12288): transpose+cast W (K x N fp32) -> Wt (N x K bf16), z = (b-8192)>>10.
__global__ __launch_bounds__(256) void prep_kernel(
    const float* __restrict__ x, u16* __restrict__ xb,
    const float* __restrict__ Wq, const float* __restrict__ Wk,
    const float* __restrict__ Wv, const float* __restrict__ Wo,
    u16* __restrict__ Wt, u16* __restrict__ Wot) {
  const int bid = blockIdx.x, tid = threadIdx.x;
  if (bid < 8192) {
    size_t i = (size_t)bid * 256 + tid;
    const float4* p = (const float4*)x;
    float4 a = p[2 * i], b = p[2 * i + 1];
    u32 w0 = (u32)f2bf(a.x) | ((u32)f2bf(a.y) << 16);
    u32 w1 = (u32)f2bf(a.z) | ((u32)f2bf(a.w) << 16);
    u32 w2 = (u32)f2bf(b.x) | ((u32)f2bf(b.y) << 16);
    u32 w3 = (u32)f2bf(b.z) | ((u32)f2bf(b.w) << 16);
    *(uint4*)(xb + 8 * i) = make_uint4(w0, w1, w2, w3);
  } else {
    __shared__ float tile[32][33];
    const int b = bid - 8192;
    const int z = b >> 10, rem = b & 1023;
    const float* W = (z == 0) ? Wq : (z == 1) ? Wk : (z == 2) ? Wv : Wo;
    u16* D = (z < 3) ? (Wt + (size_t)z * 1024 * 1024) : Wot;
    const int n0 = (rem & 31) * 32, k0 = (rem >> 5) * 32;
    const int tx = tid & 31, ty = tid >> 5;  // 32 x 8
#pragma unroll
    for (int i = 0; i < 4; i++)
      tile[ty + i * 8][tx] = W[(size_t)(k0 + ty + i * 8) * 1024 + n0 + tx];
    __syncthreads();
#pragma unroll
    for (int i = 0; i < 4; i++)
      D[(size_t)(n0 + ty + i * 8) * 1024 + k0 + tx] = f2bf(tile[tx][ty + i * 8]);
  }
}

// ---------------------------------------------------------------- GEMM: 256^2 2-phase persistent
// C[M,N] = A[M,K] * B^T with B given as Bt[N,K] (bf16 row-major). M = 16384, K = 1024 (NT=16).
// WRITE_MODE 0: C bf16.  WRITE_MODE 1: C fp32 + bias.  OT = output n-tiles per block.
//
// Geometry: BM=BN=256, BK=64, 512 threads = 8 waves as 2(M) x 4(N).
// LDS: 8 regions of 16 KiB: [buf][A/B][half], half = 128 rows x 64 k, slot s=(row*8+kc)
//   holds k-chunk (kc ^ (row&7))*8 — linear dest for gload_lds, swizzle on the global source
//   and on the ds_read address (both sides, same involution).
// Flattened tile st = o*16 + t. Phase 1: reads A0,B0,B1 (16 ds_read_b128) | stage A1(st+1) |
//   32 MFMA (M0 x N0,N1). Phase 2: reads A1 (8) | stage A0,B0,B1(st+2) | 32 MFMA (M1 x N1,N0)
//   | vmcnt(6) | barrier. Final 2 tiles stage wrapped (valid, unread).
// Per-otile C-write sits between inner loops: reads acc only, overlaps in-flight staging
//   (outstanding stores only make later vmcnt(6) conservative, never unsafe).

#define MM(FM, FN, Af, Bf)                                                      \
  do {                                                                          \
    _Pragma("unroll") for (int m_ = 0; m_ < 4; m_++)                            \
    _Pragma("unroll") for (int j_ = 0; j_ < 2; j_++)                            \
    _Pragma("unroll") for (int k_ = 0; k_ < 2; k_++)                            \
        acc[(FM) + m_][(FN) + j_] = __builtin_amdgcn_mfma_f32_16x16x32_bf16(    \
            Af[m_][k_], Bf[j_][k_], acc[(FM) + m_][(FN) + j_], 0, 0, 0);        \
  } while (0)

template <int WRITE_MODE, int OT>
__global__ __launch_bounds__(512, 2) void gemm8(const u16* __restrict__ A,
                                                const u16* __restrict__ Bt,
                                                void* __restrict__ Cv,
                                                const float* __restrict__ bias,
                                                int N) {
  constexpr int K = 1024, NT = 16;                 // BK=64 -> 16 K-tiles
  extern __shared__ __align__(16) u16 smem[];      // 8 x 16 KiB = 128 KiB
  const int t = threadIdx.x;
  const int lane = t & 63;
  const int wave = t >> 6;
  const int wm = wave >> 2;           // 0..1
  const int wn = wave & 3;            // 0..3
  const int lrow = lane & 15, lq = lane >> 4;
  const int wm64 = wm * 64, wn32 = wn * 32;

  // Block mapping (grid = 256 = 1/CU). XCD = bid%8 heuristic; each XCD owns 8 m-panels.
  const int bid = blockIdx.x;
  int bm_t, bn0;
  if (OT == 3) {            // QKV: fixed bm panel, sweep 3 n-tiles (A panels 4-way shared on-XCD)
    const int j = bid >> 3;                    // 0..31
    bm_t = ((bid & 7) << 3) | (j >> 2);        // 0..63
    bn0 = (j & 3) * 3;                         // {0,3,6,9}; otile o -> bn0+o covers 0..11
  } else {                  // out: 64 m x 4 n, one otile
    bm_t = ((bid & 7) << 3) | ((bid >> 3) & 7);
    bn0 = bid >> 6;
  }
  const size_t bm = (size_t)bm_t * 256;

  const u16* Ap = A + bm * K;
  const size_t halfK = (size_t)128 * K;

  // staging invariants: 2 issues/thread/half-tile, linear LDS dest, swizzled global source
  int srow[2], soff[2], sdst[2];
#pragma unroll
  for (int i = 0; i < 2; i++) {
    const int s = (i << 9) + t;
    srow[i] = s >> 3;
    soff[i] = ((s & 7) ^ (srow[i] & 7)) << 3;
    sdst[i] = s << 3;
  }

#define RG(buf, op, h) (smem + ((((buf) << 2) | ((op) << 1) | (h)) << 13))

  auto STG = [&](const u16* Gp, int kt, u16* L) {
#pragma unroll
    for (int i = 0; i < 2; i++)
      load_lds16(Gp + (size_t)srow[i] * K + (kt << 6) + soff[i], L + sdst[i]);
  };
  auto LDA = [&](bf16x8 (&f)[4][2], const u16* base) {
#pragma unroll
    for (int m = 0; m < 4; m++) {
      const int rh = wm64 + m * 16 + lrow;
      const int ro = rh << 6, rx = rh & 7;
#pragma unroll
      for (int ks = 0; ks < 2; ks++)
        f[m][ks] = *(const bf16x8*)&base[ro + ((((ks << 2) + lq) ^ rx) << 3)];
    }
  };
  auto LDB = [&](bf16x8 (&f)[2][2], const u16* base) {
#pragma unroll
    for (int j = 0; j < 2; j++) {
      const int ch = wn32 + j * 16 + lrow;
      const int co = ch << 6, cx = ch & 7;
#pragma unroll
      for (int ks = 0; ks < 2; ks++)
        f[j][ks] = *(const bf16x8*)&base[co + ((((ks << 2) + lq) ^ cx) << 3)];
    }
  };

  f32x4 acc[8][4];
#pragma unroll
  for (int i = 0; i < 8; i++)
#pragma unroll
    for (int j = 0; j < 4; j++) acc[i][j] = 0.0f;

  bf16x8 af[4][2], bf0[2][2], bf1[2][2];

  // prologue: stage tile0 (A0,B0,B1,A1) + tile1 (A0,B0,B1) of otile 0; full drain once.
  {
    const u16* Bp0 = Bt + (size_t)bn0 * 256 * K;
    STG(Ap, 0, RG(0, 0, 0));
    STG(Bp0, 0, RG(0, 1, 0));
    STG(Bp0 + halfK, 0, RG(0, 1, 1));
    STG(Ap + halfK, 0, RG(0, 0, 1));
    STG(Ap, 1, RG(1, 0, 0));
    STG(Bp0, 1, RG(1, 1, 0));
    STG(Bp0 + halfK, 1, RG(1, 1, 1));
  }
  asm volatile("s_waitcnt vmcnt(0)" ::: "memory");
  __builtin_amdgcn_s_barrier();

#pragma unroll 1
  for (int o = 0; o < OT; ++o) {
#pragma unroll 2
    for (int tt = 0; tt < NT; ++tt) {
      const int st = o * NT + tt;
      const int p = tt & 1;                       // NT even -> parity continuous across otiles
      int s1 = st + 1; if (s1 >= OT * NT) s1 -= NT;   // wrapped staging: valid addr, never read
      int s2 = st + 2; if (s2 >= OT * NT) s2 -= NT;
      const int t1 = s1 & 15;
      const int o2 = s2 >> 4, t2 = s2 & 15;
      const u16* B2 = Bt + (size_t)(bn0 + o2) * 256 * K;   // staging B base (may be next otile)
      const int q1 = p ^ 1, q2 = p;

      // phase 1: reads A0,B0,B1 (16) | stage A1(st+1) | MFMA M0 x {N0,N1} (32)
      __builtin_amdgcn_sched_barrier(0);   // pin phase body below the preceding s_barrier
      LDA(af, RG(p, 0, 0));
      LDB(bf0, RG(p, 1, 0));
      LDB(bf1, RG(p, 1, 1));
      STG(Ap + halfK, t1, RG(q1, 0, 1));
      __builtin_amdgcn_s_setprio(1);
      MM(0, 0, af, bf0);
      MM(0, 2, af, bf1);
      __builtin_amdgcn_s_setprio(0);
      __builtin_amdgcn_s_barrier();

      // phase 2: reads A1 (8) | stage A0,B0,B1(st+2) | MFMA M1 x {N1,N0} | vmcnt(6)
      __builtin_amdgcn_sched_barrier(0);
      LDA(af, RG(p, 0, 1));
      STG(Ap, t2, RG(q2, 0, 0));
      STG(B2, t2, RG(q2, 1, 0));
      STG(B2 + halfK, t2, RG(q2, 1, 1));
      __builtin_amdgcn_s_setprio(1);
      MM(4, 2, af, bf1);
      MM(4, 0, af, bf0);
      __builtin_amdgcn_s_setprio(0);
      asm volatile("s_waitcnt vmcnt(6)" ::: "memory");  // 3 newest half-tiles stay in flight
      __builtin_amdgcn_s_barrier();
    }

    if (o + 1 == OT)  // last otile: drain wrapped stages before ending (LDS dealloc safety)
      asm volatile("s_waitcnt vmcnt(0)" ::: "memory");

    // C-write for otile o (reads acc + global stores only; overlaps next otile's staging).
    // C/D layout: col = lane&15, row = (lane>>4)*4 + r  [verified m89/m91]
    // Nontemporal: C is write-once; keep L2 for the staging reuse window.
    {
      const size_t bcol = (size_t)(bn0 + o) * 256;
#pragma unroll
      for (int fm = 0; fm < 8; fm++) {
        const int MH = fm >> 2, fmr = fm & 3;
#pragma unroll
        for (int fn = 0; fn < 4; fn++) {
          const int NH = fn >> 1, fnr = fn & 1;
          const size_t col = bcol + NH * 128 + wn32 + fnr * 16 + lrow;
#pragma unroll
          for (int r = 0; r < 4; r++) {
            const size_t row = bm + MH * 128 + wm64 + fmr * 16 + lq * 4 + r;
            if (WRITE_MODE == 0)
              __builtin_nontemporal_store(f2bf(acc[fm][fn][r]), (u16*)Cv + row * N + col);
            else
              __builtin_nontemporal_store(acc[fm][fn][r] + bias[col],
                                          (float*)Cv + row * N + col);
          }
        }
      }
    }
    if (o + 1 < OT) {
#pragma unroll
      for (int i = 0; i < 8; i++)
#pragma unroll
        for (int j = 0; j < 4; j++) acc[i][j] = 0.0f;
    }
  }
#undef RG
}

// ---------------------------------------------------------------- attention
// One wave per token, barrier-free (each wave touches only kv[wave]).
// QKV: [tok][3072] bf16 = q(16x64) | k(16x64) | v(16x64).
// lane -> (hq = lane>>2, sub = lane&3); lane owns q[hq][sub*16..+15].
__device__ __forceinline__ void load16f(const u16* p, float* f) {
  const uint4* u = (const uint4*)p;
  uint4 a = u[0], b = u[1];
  f[0] = bflo(a.x);  f[1] = bfhi(a.x);  f[2] = bflo(a.y);  f[3] = bfhi(a.y);
  f[4] = bflo(a.z);  f[5] = bfhi(a.z);  f[6] = bflo(a.w);  f[7] = bfhi(a.w);
  f[8] = bflo(b.x);  f[9] = bfhi(b.x);  f[10] = bflo(b.y); f[11] = bfhi(b.y);
  f[12] = bflo(b.z); f[13] = bfhi(b.z); f[14] = bflo(b.w); f[15] = bfhi(b.w);
}

__global__ __launch_bounds__(256) void attn_kernel(const u16* __restrict__ QKV,
                                                   u16* __restrict__ AO) {
  __shared__ u16 kv[4][2048];  // per wave: k[0..1023], v[1024..2047]
  const int t = threadIdx.x, lane = t & 63, wave = t >> 6;
  const int sub = lane & 3;
  const int tok = blockIdx.x * 4 + wave;   // grid 4096 -> 16384 tokens

  const u16* base = QKV + (size_t)tok * 3072;
  uint4 k0 = ((const uint4*)(base + 1024))[2 * lane];
  uint4 k1 = ((const uint4*)(base + 1024))[2 * lane + 1];
  uint4 v0 = ((const uint4*)(base + 2048))[2 * lane];
  uint4 v1 = ((const uint4*)(base + 2048))[2 * lane + 1];
  float qf[16];
  load16f(base + lane * 16, qf);  // hq*64 + sub*16 == lane*16
  ((uint4*)&kv[wave][0])[2 * lane] = k0;
  ((uint4*)&kv[wave][0])[2 * lane + 1] = k1;
  ((uint4*)&kv[wave][1024])[2 * lane] = v0;
  ((uint4*)&kv[wave][1024])[2 * lane + 1] = v1;
  // no barrier: same-wave ds_write -> ds_read ordering enforced by compiler waitcnt

  float e[16];
#pragma unroll
  for (int hk = 0; hk < 16; hk++) {
    float kf[16];
    load16f(&kv[wave][hk * 64 + sub * 16], kf);
    float s = 0.f;
#pragma unroll
    for (int i = 0; i < 16; i++) s = fmaf(qf[i], kf[i], s);
    s += __shfl_xor(s, 1);
    s += __shfl_xor(s, 2);
    e[hk] = s;
  }

  float m = e[0];
#pragma unroll
  for (int hk = 1; hk < 16; hk++) m = fmaxf(m, e[hk]);
  float sum = 0.f;
#pragma unroll
  for (int hk = 0; hk < 16; hk++) {
    float p = __expf((e[hk] - m) * 0.03125f);
    e[hk] = p;
    sum += p;
  }
  float inv = 1.0f / sum;

  float o[16];
#pragma unroll
  for (int i = 0; i < 16; i++) o[i] = 0.f;
#pragma unroll
  for (int hk = 0; hk < 16; hk++) {
    float a = e[hk] * inv;
    float vf[16];
    load16f(&kv[wave][1024 + hk * 64 + sub * 16], vf);
#pragma unroll
    for (int i = 0; i < 16; i++) o[i] = fmaf(a, vf[i], o[i]);
  }

  u32 w[8];
#pragma unroll
  for (int i = 0; i < 8; i++)
    w[i] = (u32)f2bf(o[2 * i]) | ((u32)f2bf(o[2 * i + 1]) << 16);
  uint4* dst = (uint4*)(AO + (size_t)tok * 1024 + lane * 16);
  dst[0] = make_uint4(w[0], w[1], w[2], w[3]);
  dst[1] = make_uint4(w[4], w[5], w[6], w[7]);
}

// ---------------------------------------------------------------- launch

extern "C" void kernel_launch(void* const* d_in, const int* in_sizes, int n_in,
                              void* d_out, int out_size, void* d_ws, size_t ws_size,
                              hipStream_t stream) {
  const float* x = (const float*)d_in[0];
  const float* Wq = (const float*)d_in[1];
  const float* Wk = (const float*)d_in[2];
  const float* Wv = (const float*)d_in[3];
  const float* Wo = (const float*)d_in[4];
  const float* bo = (const float*)d_in[5];
  float* out = (float*)d_out;

  char* ws = (char*)d_ws;
  u16* Xb  = (u16*)(ws);                    // 16384*1024*2 = 33,554,432
  u16* Wt  = (u16*)(ws + 33554432);         // 3072*1024*2  =  6,291,456
  u16* Wot = (u16*)(ws + 39845888);         // 1024*1024*2  =  2,097,152
  u16* QKV = (u16*)(ws + 41943040);         // 16384*3072*2 = 100,663,296
  u16* AO  = (u16*)(ws + 142606336);        // 16384*1024*2 = 33,554,432  (total 176,160,768)

  // 128 KiB dynamic LDS needs the opt-in attribute (host-side, capture-safe)
  hipFuncSetAttribute(reinterpret_cast<const void*>(&gemm8<0, 3>),
                      hipFuncAttributeMaxDynamicSharedMemorySize, 131072);
  hipFuncSetAttribute(reinterpret_cast<const void*>(&gemm8<1, 1>),
                      hipFuncAttributeMaxDynamicSharedMemorySize, 131072);

  prep_kernel<<<12288, 256, 0, stream>>>(x, Xb, Wq, Wk, Wv, Wo, Wt, Wot);
  gemm8<0, 3><<<256, 512, 131072, stream>>>(Xb, Wt, QKV, nullptr, 3072);
  attn_kernel<<<4096, 256, 0, stream>>>(QKV, AO);
  gemm8<1, 1><<<256, 512, 131072, stream>>>(AO, Wot, out, bo, 1024);
}

// Round 4
// 293.957 us; speedup vs baseline: 1.1487x; 1.1487x over previous
//
#include <hip/hip_runtime.h>

// MultiHeadAttention (cross-head variant): out = softmax((XWq)(XWk)^T/32 per-token over heads) (XWv) Wo + bo
// Pipeline: merged cast/transpose -> fused QKV bf16 GEMM -> barrier-free per-token wave attention
//           -> out GEMM + bias.
// R9 change: R8 minus nontemporal C stores (single-variable revert).
//   R8 counters showed WRITE_SIZE 100->188 MB (nt stores of 2B elements bypass L2 write
//   coalescing -> partial-line writeback amplification) and MfmaUtil 39.5->30.0 which is
//   EXACTLY the dilution 39.5*(107.5/141.5) -- MFMA pipeline unchanged, all loss from the
//   store tax. So the 2-phase slip structure itself is still unmeasured; this round
//   isolates it: 2 phases/tile, one barrier per phase, no mid-phase lgkmcnt(0) drain
//   (compiler emits counted waits), setprio(1) around MFMA clusters, vmcnt(6) at tile end.

typedef unsigned short u16;
typedef unsigned int u32;

typedef __bf16 bf16x8 __attribute__((ext_vector_type(8)));
typedef float f32x4 __attribute__((ext_vector_type(4)));

__device__ __forceinline__ u16 f2bf(float f) {
  u32 u = __float_as_uint(f);
  u += 0x7fffu + ((u >> 16) & 1u);   // round-to-nearest-even
  return (u16)(u >> 16);
}
__device__ __forceinline__ float bflo(u32 u) { return __uint_as_float(u << 16); }
__device__ __forceinline__ float bfhi(u32 u) { return __uint_as_float(u & 0xffff0000u); }

// async global->LDS, 16B per lane. LDS dest must be wave-uniform base + lane*16.
__device__ __forceinline__ void load_lds16(const u16* g, u16* l) {
  __builtin_amdgcn_global_load_lds(
      (const __attribute__((address_space(1))) u32*)g,
      (__attribute__((address_space(3))) u32*)l, 16, 0, 0);
}

// ---------------------------------------------------------------- prep (merged)
// blocks [0, 8192): cast x fp32 -> bf16, 8 elems/thread.
// blocks [8192, 12288): transpose+cast W (K x N fp32) -> Wt (N x K bf16), z = (b-8192)>>10.
__global__ __launch_bounds__(256) void prep_kernel(
    const float* __restrict__ x, u16* __restrict__ xb,
    const float* __restrict__ Wq, const float* __restrict__ Wk,
    const float* __restrict__ Wv, const float* __restrict__ Wo,
    u16* __restrict__ Wt, u16* __restrict__ Wot) {
  const int bid = blockIdx.x, tid = threadIdx.x;
  if (bid < 8192) {
    size_t i = (size_t)bid * 256 + tid;
    const float4* p = (const float4*)x;
    float4 a = p[2 * i], b = p[2 * i + 1];
    u32 w0 = (u32)f2bf(a.x) | ((u32)f2bf(a.y) << 16);
    u32 w1 = (u32)f2bf(a.z) | ((u32)f2bf(a.w) << 16);
    u32 w2 = (u32)f2bf(b.x) | ((u32)f2bf(b.y) << 16);
    u32 w3 = (u32)f2bf(b.z) | ((u32)f2bf(b.w) << 16);
    *(uint4*)(xb + 8 * i) = make_uint4(w0, w1, w2, w3);
  } else {
    __shared__ float tile[32][33];
    const int b = bid - 8192;
    const int z = b >> 10, rem = b & 1023;
    const float* W = (z == 0) ? Wq : (z == 1) ? Wk : (z == 2) ? Wv : Wo;
    u16* D = (z < 3) ? (Wt + (size_t)z * 1024 * 1024) : Wot;
    const int n0 = (rem & 31) * 32, k0 = (rem >> 5) * 32;
    const int tx = tid & 31, ty = tid >> 5;  // 32 x 8
#pragma unroll
    for (int i = 0; i < 4; i++)
      tile[ty + i * 8][tx] = W[(size_t)(k0 + ty + i * 8) * 1024 + n0 + tx];
    __syncthreads();
#pragma unroll
    for (int i = 0; i < 4; i++)
      D[(size_t)(n0 + ty + i * 8) * 1024 + k0 + tx] = f2bf(tile[tx][ty + i * 8]);
  }
}

// ---------------------------------------------------------------- GEMM: 256^2 2-phase persistent
// C[M,N] = A[M,K] * B^T with B given as Bt[N,K] (bf16 row-major). M = 16384, K = 1024 (NT=16).
// WRITE_MODE 0: C bf16.  WRITE_MODE 1: C fp32 + bias.  OT = output n-tiles per block.
//
// Geometry: BM=BN=256, BK=64, 512 threads = 8 waves as 2(M) x 4(N).
// LDS: 8 regions of 16 KiB: [buf][A/B][half], half = 128 rows x 64 k, slot s=(row*8+kc)
//   holds k-chunk (kc ^ (row&7))*8 — linear dest for gload_lds, swizzle on the global source
//   and on the ds_read address (both sides, same involution).
// Flattened tile st = o*16 + t. Phase 1: reads A0,B0,B1 (16 ds_read_b128) | stage A1(st+1) |
//   32 MFMA (M0 x N0,N1). Phase 2: reads A1 (8) | stage A0,B0,B1(st+2) | 32 MFMA (M1 x N1,N0)
//   | vmcnt(6) | barrier. Final 2 tiles stage wrapped (valid, unread).
// Per-otile C-write sits between inner loops: reads acc only, overlaps in-flight staging
//   (outstanding stores only make later vmcnt(6) conservative, never unsafe).

#define MM(FM, FN, Af, Bf)                                                      \
  do {                                                                          \
    _Pragma("unroll") for (int m_ = 0; m_ < 4; m_++)                            \
    _Pragma("unroll") for (int j_ = 0; j_ < 2; j_++)                            \
    _Pragma("unroll") for (int k_ = 0; k_ < 2; k_++)                            \
        acc[(FM) + m_][(FN) + j_] = __builtin_amdgcn_mfma_f32_16x16x32_bf16(    \
            Af[m_][k_], Bf[j_][k_], acc[(FM) + m_][(FN) + j_], 0, 0, 0);        \
  } while (0)

template <int WRITE_MODE, int OT>
__global__ __launch_bounds__(512, 2) void gemm8(const u16* __restrict__ A,
                                                const u16* __restrict__ Bt,
                                                void* __restrict__ Cv,
                                                const float* __restrict__ bias,
                                                int N) {
  constexpr int K = 1024, NT = 16;                 // BK=64 -> 16 K-tiles
  extern __shared__ __align__(16) u16 smem[];      // 8 x 16 KiB = 128 KiB
  const int t = threadIdx.x;
  const int lane = t & 63;
  const int wave = t >> 6;
  const int wm = wave >> 2;           // 0..1
  const int wn = wave & 3;            // 0..3
  const int lrow = lane & 15, lq = lane >> 4;
  const int wm64 = wm * 64, wn32 = wn * 32;

  // Block mapping (grid = 256 = 1/CU). XCD = bid%8 heuristic; each XCD owns 8 m-panels.
  const int bid = blockIdx.x;
  int bm_t, bn0;
  if (OT == 3) {            // QKV: fixed bm panel, sweep 3 n-tiles (A panels 4-way shared on-XCD)
    const int j = bid >> 3;                    // 0..31
    bm_t = ((bid & 7) << 3) | (j >> 2);        // 0..63
    bn0 = (j & 3) * 3;                         // {0,3,6,9}; otile o -> bn0+o covers 0..11
  } else {                  // out: 64 m x 4 n, one otile
    bm_t = ((bid & 7) << 3) | ((bid >> 3) & 7);
    bn0 = bid >> 6;
  }
  const size_t bm = (size_t)bm_t * 256;

  const u16* Ap = A + bm * K;
  const size_t halfK = (size_t)128 * K;

  // staging invariants: 2 issues/thread/half-tile, linear LDS dest, swizzled global source
  int srow[2], soff[2], sdst[2];
#pragma unroll
  for (int i = 0; i < 2; i++) {
    const int s = (i << 9) + t;
    srow[i] = s >> 3;
    soff[i] = ((s & 7) ^ (srow[i] & 7)) << 3;
    sdst[i] = s << 3;
  }

#define RG(buf, op, h) (smem + ((((buf) << 2) | ((op) << 1) | (h)) << 13))

  auto STG = [&](const u16* Gp, int kt, u16* L) {
#pragma unroll
    for (int i = 0; i < 2; i++)
      load_lds16(Gp + (size_t)srow[i] * K + (kt << 6) + soff[i], L + sdst[i]);
  };
  auto LDA = [&](bf16x8 (&f)[4][2], const u16* base) {
#pragma unroll
    for (int m = 0; m < 4; m++) {
      const int rh = wm64 + m * 16 + lrow;
      const int ro = rh << 6, rx = rh & 7;
#pragma unroll
      for (int ks = 0; ks < 2; ks++)
        f[m][ks] = *(const bf16x8*)&base[ro + ((((ks << 2) + lq) ^ rx) << 3)];
    }
  };
  auto LDB = [&](bf16x8 (&f)[2][2], const u16* base) {
#pragma unroll
    for (int j = 0; j < 2; j++) {
      const int ch = wn32 + j * 16 + lrow;
      const int co = ch << 6, cx = ch & 7;
#pragma unroll
      for (int ks = 0; ks < 2; ks++)
        f[j][ks] = *(const bf16x8*)&base[co + ((((ks << 2) + lq) ^ cx) << 3)];
    }
  };

  f32x4 acc[8][4];
#pragma unroll
  for (int i = 0; i < 8; i++)
#pragma unroll
    for (int j = 0; j < 4; j++) acc[i][j] = 0.0f;

  bf16x8 af[4][2], bf0[2][2], bf1[2][2];

  // prologue: stage tile0 (A0,B0,B1,A1) + tile1 (A0,B0,B1) of otile 0; full drain once.
  {
    const u16* Bp0 = Bt + (size_t)bn0 * 256 * K;
    STG(Ap, 0, RG(0, 0, 0));
    STG(Bp0, 0, RG(0, 1, 0));
    STG(Bp0 + halfK, 0, RG(0, 1, 1));
    STG(Ap + halfK, 0, RG(0, 0, 1));
    STG(Ap, 1, RG(1, 0, 0));
    STG(Bp0, 1, RG(1, 1, 0));
    STG(Bp0 + halfK, 1, RG(1, 1, 1));
  }
  asm volatile("s_waitcnt vmcnt(0)" ::: "memory");
  __builtin_amdgcn_s_barrier();

#pragma unroll 1
  for (int o = 0; o < OT; ++o) {
#pragma unroll 2
    for (int tt = 0; tt < NT; ++tt) {
      const int st = o * NT + tt;
      const int p = tt & 1;                       // NT even -> parity continuous across otiles
      int s1 = st + 1; if (s1 >= OT * NT) s1 -= NT;   // wrapped staging: valid addr, never read
      int s2 = st + 2; if (s2 >= OT * NT) s2 -= NT;
      const int t1 = s1 & 15;
      const int o2 = s2 >> 4, t2 = s2 & 15;
      const u16* B2 = Bt + (size_t)(bn0 + o2) * 256 * K;   // staging B base (may be next otile)
      const int q1 = p ^ 1, q2 = p;

      // phase 1: reads A0,B0,B1 (16) | stage A1(st+1) | MFMA M0 x {N0,N1} (32)
      __builtin_amdgcn_sched_barrier(0);   // pin phase body below the preceding s_barrier
      LDA(af, RG(p, 0, 0));
      LDB(bf0, RG(p, 1, 0));
      LDB(bf1, RG(p, 1, 1));
      STG(Ap + halfK, t1, RG(q1, 0, 1));
      __builtin_amdgcn_s_setprio(1);
      MM(0, 0, af, bf0);
      MM(0, 2, af, bf1);
      __builtin_amdgcn_s_setprio(0);
      __builtin_amdgcn_s_barrier();

      // phase 2: reads A1 (8) | stage A0,B0,B1(st+2) | MFMA M1 x {N1,N0} | vmcnt(6)
      __builtin_amdgcn_sched_barrier(0);
      LDA(af, RG(p, 0, 1));
      STG(Ap, t2, RG(q2, 0, 0));
      STG(B2, t2, RG(q2, 1, 0));
      STG(B2 + halfK, t2, RG(q2, 1, 1));
      __builtin_amdgcn_s_setprio(1);
      MM(4, 2, af, bf1);
      MM(4, 0, af, bf0);
      __builtin_amdgcn_s_setprio(0);
      asm volatile("s_waitcnt vmcnt(6)" ::: "memory");  // 3 newest half-tiles stay in flight
      __builtin_amdgcn_s_barrier();
    }

    if (o + 1 == OT)  // last otile: drain wrapped stages before ending (LDS dealloc safety)
      asm volatile("s_waitcnt vmcnt(0)" ::: "memory");

    // C-write for otile o (reads acc + global stores only; overlaps in-flight staging).
    // C/D layout: col = lane&15, row = (lane>>4)*4 + r  [verified m89/m91]
    // Plain cached stores: L2 coalesces the 2B/4B lane stores into full-line writebacks
    // (R8's nontemporal variant caused 1.9x write amplification: 100->188 MB).
    {
      const size_t bcol = (size_t)(bn0 + o) * 256;
#pragma unroll
      for (int fm = 0; fm < 8; fm++) {
        const int MH = fm >> 2, fmr = fm & 3;
#pragma unroll
        for (int fn = 0; fn < 4; fn++) {
          const int NH = fn >> 1, fnr = fn & 1;
          const size_t col = bcol + NH * 128 + wn32 + fnr * 16 + lrow;
#pragma unroll
          for (int r = 0; r < 4; r++) {
            const size_t row = bm + MH * 128 + wm64 + fmr * 16 + lq * 4 + r;
            if (WRITE_MODE == 0)
              ((u16*)Cv)[row * N + col] = f2bf(acc[fm][fn][r]);
            else
              ((float*)Cv)[row * N + col] = acc[fm][fn][r] + bias[col];
          }
        }
      }
    }
    if (o + 1 < OT) {
#pragma unroll
      for (int i = 0; i < 8; i++)
#pragma unroll
        for (int j = 0; j < 4; j++) acc[i][j] = 0.0f;
    }
  }
#undef RG
}

// ---------------------------------------------------------------- attention
// One wave per token, barrier-free (each wave touches only kv[wave]).
// QKV: [tok][3072] bf16 = q(16x64) | k(16x64) | v(16x64).
// lane -> (hq = lane>>2, sub = lane&3); lane owns q[hq][sub*16..+15].
__device__ __forceinline__ void load16f(const u16* p, float* f) {
  const uint4* u = (const uint4*)p;
  uint4 a = u[0], b = u[1];
  f[0] = bflo(a.x);  f[1] = bfhi(a.x);  f[2] = bflo(a.y);  f[3] = bfhi(a.y);
  f[4] = bflo(a.z);  f[5] = bfhi(a.z);  f[6] = bflo(a.w);  f[7] = bfhi(a.w);
  f[8] = bflo(b.x);  f[9] = bfhi(b.x);  f[10] = bflo(b.y); f[11] = bfhi(b.y);
  f[12] = bflo(b.z); f[13] = bfhi(b.z); f[14] = bflo(b.w); f[15] = bfhi(b.w);
}

__global__ __launch_bounds__(256) void attn_kernel(const u16* __restrict__ QKV,
                                                   u16* __restrict__ AO) {
  __shared__ u16 kv[4][2048];  // per wave: k[0..1023], v[1024..2047]
  const int t = threadIdx.x, lane = t & 63, wave = t >> 6;
  const int sub = lane & 3;
  const int tok = blockIdx.x * 4 + wave;   // grid 4096 -> 16384 tokens

  const u16* base = QKV + (size_t)tok * 3072;
  uint4 k0 = ((const uint4*)(base + 1024))[2 * lane];
  uint4 k1 = ((const uint4*)(base + 1024))[2 * lane + 1];
  uint4 v0 = ((const uint4*)(base + 2048))[2 * lane];
  uint4 v1 = ((const uint4*)(base + 2048))[2 * lane + 1];
  float qf[16];
  load16f(base + lane * 16, qf);  // hq*64 + sub*16 == lane*16
  ((uint4*)&kv[wave][0])[2 * lane] = k0;
  ((uint4*)&kv[wave][0])[2 * lane + 1] = k1;
  ((uint4*)&kv[wave][1024])[2 * lane] = v0;
  ((uint4*)&kv[wave][1024])[2 * lane + 1] = v1;
  // no barrier: same-wave ds_write -> ds_read ordering enforced by compiler waitcnt

  float e[16];
#pragma unroll
  for (int hk = 0; hk < 16; hk++) {
    float kf[16];
    load16f(&kv[wave][hk * 64 + sub * 16], kf);
    float s = 0.f;
#pragma unroll
    for (int i = 0; i < 16; i++) s = fmaf(qf[i], kf[i], s);
    s += __shfl_xor(s, 1);
    s += __shfl_xor(s, 2);
    e[hk] = s;
  }

  float m = e[0];
#pragma unroll
  for (int hk = 1; hk < 16; hk++) m = fmaxf(m, e[hk]);
  float sum = 0.f;
#pragma unroll
  for (int hk = 0; hk < 16; hk++) {
    float p = __expf((e[hk] - m) * 0.03125f);
    e[hk] = p;
    sum += p;
  }
  float inv = 1.0f / sum;

  float o[16];
#pragma unroll
  for (int i = 0; i < 16; i++) o[i] = 0.f;
#pragma unroll
  for (int hk = 0; hk < 16; hk++) {
    float a = e[hk] * inv;
    float vf[16];
    load16f(&kv[wave][1024 + hk * 64 + sub * 16], vf);
#pragma unroll
    for (int i = 0; i < 16; i++) o[i] = fmaf(a, vf[i], o[i]);
  }

  u32 w[8];
#pragma unroll
  for (int i = 0; i < 8; i++)
    w[i] = (u32)f2bf(o[2 * i]) | ((u32)f2bf(o[2 * i + 1]) << 16);
  uint4* dst = (uint4*)(AO + (size_t)tok * 1024 + lane * 16);
  dst[0] = make_uint4(w[0], w[1], w[2], w[3]);
  dst[1] = make_uint4(w[4], w[5], w[6], w[7]);
}

// ---------------------------------------------------------------- launch

extern "C" void kernel_launch(void* const* d_in, const int* in_sizes, int n_in,
                              void* d_out, int out_size, void* d_ws, size_t ws_size,
                              hipStream_t stream) {
  const float* x = (const float*)d_in[0];
  const float* Wq = (const float*)d_in[1];
  const float* Wk = (const float*)d_in[2];
  const float* Wv = (const float*)d_in[3];
  const float* Wo = (const float*)d_in[4];
  const float* bo = (const float*)d_in[5];
  float* out = (float*)d_out;

  char* ws = (char*)d_ws;
  u16* Xb  = (u16*)(ws);                    // 16384*1024*2 = 33,554,432
  u16* Wt  = (u16*)(ws + 33554432);         // 3072*1024*2  =  6,291,456
  u16* Wot = (u16*)(ws + 39845888);         // 1024*1024*2  =  2,097,152
  u16* QKV = (u16*)(ws + 41943040);         // 16384*3072*2 = 100,663,296
  u16* AO  = (u16*)(ws + 142606336);        // 16384*1024*2 = 33,554,432  (total 176,160,768)

  // 128 KiB dynamic LDS needs the opt-in attribute (host-side, capture-safe)
  hipFuncSetAttribute(reinterpret_cast<const void*>(&gemm8<0, 3>),
                      hipFuncAttributeMaxDynamicSharedMemorySize, 131072);
  hipFuncSetAttribute(reinterpret_cast<const void*>(&gemm8<1, 1>),
                      hipFuncAttributeMaxDynamicSharedMemorySize, 131072);

  prep_kernel<<<12288, 256, 0, stream>>>(x, Xb, Wq, Wk, Wv, Wo, Wt, Wot);
  gemm8<0, 3><<<256, 512, 131072, stream>>>(Xb, Wt, QKV, nullptr, 3072);
  attn_kernel<<<4096, 256, 0, stream>>>(QKV, AO);
  gemm8<1, 1><<<256, 512, 131072, stream>>>(AO, Wot, out, bo, 1024);
}